// Round 32
// baseline (291.487 us; speedup 1.0000x reference)
//
#include <hip/hip_runtime.h>
#include <math.h>

#define HID 64
#define LR_ATT 0.2f
#define LR_ACT 0.01f
#define BSHIFT 8          // bucket = dst >> 8 (256 dsts per bucket)
#define TILE 2048         // edges per bucket_scatter tile

// ---------------- CSR build via 2-level LDS bucket sort (no per-edge global atomics) ----------------

// Pass A: global bucket histogram, LDS-aggregated (one global atomic per block x bucket).
__global__ __launch_bounds__(256) void bucket_hist_kernel(
    const int* __restrict__ dst, int* __restrict__ bucket_counts, int E, int NB)
{
    __shared__ int h[256];
    h[threadIdx.x] = 0;
    __syncthreads();
    int i = blockIdx.x * blockDim.x + threadIdx.x;
    int stride = gridDim.x * blockDim.x;
    for (; i < E; i += stride) atomicAdd(&h[dst[i] >> BSHIFT], 1);
    __syncthreads();
    if (threadIdx.x < NB && h[threadIdx.x])
        atomicAdd(&bucket_counts[threadIdx.x], h[threadIdx.x]);
}

// Scan NB (<=256) bucket counts -> bucket_off[NB+1]; init cursor; offsets[n]=E.
__global__ __launch_bounds__(256) void bucket_scan_kernel(
    const int* __restrict__ bucket_counts, int* __restrict__ bucket_off,
    int* __restrict__ cursor, int* __restrict__ offsets, int NB, int n, int E)
{
    __shared__ int sd[256];
    const int t = threadIdx.x;
    int v = (t < NB) ? bucket_counts[t] : 0;
    sd[t] = v;
    __syncthreads();
    for (int off = 1; off < 256; off <<= 1) {
        int u = (t >= off) ? sd[t - off] : 0;
        __syncthreads();
        sd[t] += u;
        __syncthreads();
    }
    int excl = sd[t] - v;
    if (t < NB) { bucket_off[t] = excl; cursor[t] = excl; }
    if (t == 255) { bucket_off[NB] = sd[255]; offsets[n] = E; }
}

// Pass B: scatter edges into bucket regions. Per tile: LDS rank+scan, one
// reservation atomic per bucket, LDS reorder, then near-coalesced u64 writes.
__global__ __launch_bounds__(256) void bucket_scatter_kernel(
    const int* __restrict__ src, const int* __restrict__ dst,
    int* __restrict__ cursor, unsigned long long* __restrict__ bucketed,
    int E, int NB)
{
    constexpr int EPT = TILE / 256;  // edges per thread
    __shared__ int cnt[256], lo[256], gb[256];
    __shared__ unsigned long long stg[TILE];

    const int t = threadIdx.x;
    const int base = blockIdx.x * TILE;
    const int tcount = min(TILE, E - base);

    cnt[t] = 0;
    __syncthreads();

    unsigned long long e[EPT];
    int r[EPT], bb[EPT];
    #pragma unroll
    for (int j = 0; j < EPT; ++j) {
        int idx = base + j * 256 + t;
        if (idx < E) {
            int d = dst[idx], s = src[idx];
            e[j]  = ((unsigned long long)(unsigned)d << 32) | (unsigned)s;
            bb[j] = d >> BSHIFT;
            r[j]  = atomicAdd(&cnt[bb[j]], 1);
        } else {
            bb[j] = -1;
        }
    }
    __syncthreads();

    const int v = cnt[t];
    lo[t] = v;
    __syncthreads();
    for (int off = 1; off < 256; off <<= 1) {
        int u = (t >= off) ? lo[t - off] : 0;
        __syncthreads();
        lo[t] += u;
        __syncthreads();
    }
    const int excl = lo[t] - v;
    __syncthreads();
    lo[t] = excl;
    if (t < NB) gb[t] = atomicAdd(&cursor[t], v);
    __syncthreads();

    #pragma unroll
    for (int j = 0; j < EPT; ++j)
        if (bb[j] >= 0) stg[lo[bb[j]] + r[j]] = e[j];
    __syncthreads();

    for (int j = t; j < tcount; j += 256) {
        unsigned long long ev = stg[j];
        int b = (int)(ev >> 32) >> BSHIFT;
        bucketed[gb[b] + (j - lo[b])] = ev;
    }
}

// Pass C: one block per bucket -- exact within-bucket sort by dst; emits
// sorted_src and per-dst offsets. All LDS atomics; coalesced-run writes.
__global__ __launch_bounds__(256) void bucket_sort_kernel(
    const unsigned long long* __restrict__ bucketed,
    const int* __restrict__ bucket_off,
    int* __restrict__ sorted_src, int* __restrict__ offsets, int n)
{
    __shared__ int dcnt[256], loff[256], cur[256];
    const int b = blockIdx.x, t = threadIdx.x;
    const int bo = bucket_off[b], bo1 = bucket_off[b + 1];

    dcnt[t] = 0;
    __syncthreads();
    for (int j = bo + t; j < bo1; j += 256)
        atomicAdd(&dcnt[(int)(bucketed[j] >> 32) & 255], 1);
    __syncthreads();

    const int v = dcnt[t];
    loff[t] = v;
    __syncthreads();
    for (int off = 1; off < 256; off <<= 1) {
        int u = (t >= off) ? loff[t - off] : 0;
        __syncthreads();
        loff[t] += u;
        __syncthreads();
    }
    const int excl = loff[t] - v;
    __syncthreads();
    loff[t] = excl;
    cur[t]  = excl;
    __syncthreads();

    const int d_global = (b << BSHIFT) + t;
    if (d_global < n) offsets[d_global] = bo + excl;

    for (int j = bo + t; j < bo1; j += 256) {
        unsigned long long ev = bucketed[j];
        int d = (int)(ev >> 32);
        int slot = atomicAdd(&cur[d & 255], 1);
        sorted_src[bo + slot] = (int)(ev & 0xffffffffu);
    }
}

// ---------------- per-layer kernels ----------------

// Block-tiled GEMM: block = TR nodes x 64 channels (see r24 notes).
template<int K>
__global__ __launch_bounds__(256) void gemm_tile_kernel(
    const float* __restrict__ hin, const float* __restrict__ W,
    const float* __restrict__ a_src, const float* __restrict__ a_dst,
    float* __restrict__ hout, float* __restrict__ al_s, float* __restrict__ al_d,
    int n_nodes)
{
    constexpr int TR = (K > 64) ? 32 : 64;
    constexpr int NR = TR / 16;
    constexpr int KP = K + 4;
    constexpr int NK4 = K / 4;

    __shared__ float ws[K * HID];
    __shared__ float xs[TR * KP];

    const int t = threadIdx.x;
    const int base = blockIdx.x * TR;

    for (int i = t; i < K * HID; i += 256) ws[i] = W[i];

    for (int f = t; f < TR * NK4; f += 256) {
        int row = f / NK4, k4 = f % NK4;
        if (base + row < n_nodes)
            *(float4*)&xs[row * KP + k4 * 4] =
                *(const float4*)(hin + (size_t)(base + row) * K + k4 * 4);
    }
    __syncthreads();

    const int ch0 = (t & 15) * 4;
    const int ng  = (t >> 4) * NR;

    float4 acc[NR];
    #pragma unroll
    for (int j = 0; j < NR; ++j) acc[j] = float4{0.f, 0.f, 0.f, 0.f};

    #pragma unroll 4
    for (int k = 0; k < K; ++k) {
        const float4 wv = *(const float4*)&ws[k * HID + ch0];
        #pragma unroll
        for (int j = 0; j < NR; ++j) {
            const float xv = xs[(ng + j) * KP + k];
            acc[j].x = fmaf(xv, wv.x, acc[j].x);
            acc[j].y = fmaf(xv, wv.y, acc[j].y);
            acc[j].z = fmaf(xv, wv.z, acc[j].z);
            acc[j].w = fmaf(xv, wv.w, acc[j].w);
        }
    }

    const float4 as4 = *(const float4*)&a_src[ch0];
    const float4 ad4 = *(const float4*)&a_dst[ch0];

    #pragma unroll
    for (int j = 0; j < NR; ++j) {
        const int row = base + ng + j;
        if (row < n_nodes) {
            *(float4*)&hout[(size_t)row * HID + ch0] = acc[j];
            float ps = acc[j].x * as4.x + acc[j].y * as4.y
                     + acc[j].z * as4.z + acc[j].w * as4.w;
            float pd = acc[j].x * ad4.x + acc[j].y * ad4.y
                     + acc[j].z * ad4.z + acc[j].w * ad4.w;
            #pragma unroll
            for (int off = 8; off; off >>= 1) {
                ps += __shfl_xor(ps, off);
                pd += __shfl_xor(pd, off);
            }
            if ((t & 15) == 0) {
                al_s[row] = ps;
                al_d[row] = pd;
            }
        }
    }
}

// One wave per dst node; precomputed softmax, FOUR independent gather+fma
// streams (16 edges/iteration) for maximum memory-level parallelism.
template<bool FUSE_HEAD>
__global__ __launch_bounds__(256) void node_agg_kernel(
    const int* __restrict__ offsets, const int* __restrict__ sorted_src,
    const float* __restrict__ al_s, const float* __restrict__ al_d,
    const float* __restrict__ h, const float* __restrict__ b,
    float* __restrict__ hout,
    const float* __restrict__ Wout, const float* __restrict__ bout,
    float* __restrict__ out, int n_nodes)
{
    const int lane = threadIdx.x & 63;
    const int q    = lane >> 4;
    const int ch   = (lane & 15) * 4;
    const int wib  = threadIdx.x >> 6;
    const int wpb  = blockDim.x >> 6;
    int wid = blockIdx.x * wpb + wib;
    int nw  = gridDim.x * wpb;

    const float4 bc = *(const float4*)&b[ch];
    const float4 wc = FUSE_HEAD ? *(const float4*)&Wout[ch] : float4{0.f,0.f,0.f,0.f};

    for (int d = wid; d < n_nodes; d += nw) {
        const float ald = al_d[d];
        float e0 = al_s[d] + ald;
        e0 = (e0 > 0.f) ? e0 : LR_ATT * e0;

        const int k0  = offsets[d];
        const int k1  = offsets[d + 1];
        const int deg = k1 - k0;

        int   sA = d;
        float eA = __int_as_float(0xff800000);
        if (lane < deg) {
            sA = sorted_src[k0 + lane];
            float e = al_s[sA] + ald;
            eA = (e > 0.f) ? e : LR_ATT * e;
        }
        float lm = fmaxf(e0, eA);
        for (int k = k0 + 64 + lane; k < k1; k += 64) {
            int s = sorted_src[k];
            float e = al_s[s] + ald;
            e = (e > 0.f) ? e : LR_ATT * e;
            lm = fmaxf(lm, e);
        }
        #pragma unroll
        for (int off = 32; off; off >>= 1)
            lm = fmaxf(lm, __shfl_xor(lm, off));
        const float m = lm;

        const float ex0 = __expf(e0 - m);
        float pA = (lane < deg) ? __expf(eA - m) : 0.f;
        float ssum = pA;
        #pragma unroll
        for (int off = 32; off; off >>= 1) ssum += __shfl_xor(ssum, off);
        float sum = ssum + ex0;

        const float4 hd = *(const float4*)&h[(size_t)d * HID + ch];
        float exq = (q == 0) ? ex0 : 0.f;
        float4 a0, a1, a2, a3;
        a0.x = exq * hd.x; a0.y = exq * hd.y;
        a0.z = exq * hd.z; a0.w = exq * hd.w;
        a1 = float4{0.f,0.f,0.f,0.f};
        a2 = float4{0.f,0.f,0.f,0.f};
        a3 = float4{0.f,0.f,0.f,0.f};

        const int mainN = min(deg, 64);
        int k = 0;
        for (; k + 16 <= mainN; k += 16) {
            int   s0 = __shfl(sA, k + q);
            float p0 = __shfl(pA, k + q);
            int   s1 = __shfl(sA, k + 4 + q);
            float p1 = __shfl(pA, k + 4 + q);
            int   s2 = __shfl(sA, k + 8 + q);
            float p2 = __shfl(pA, k + 8 + q);
            int   s3 = __shfl(sA, k + 12 + q);
            float p3 = __shfl(pA, k + 12 + q);
            const float4 hv0 = *(const float4*)&h[(size_t)s0 * HID + ch];
            const float4 hv1 = *(const float4*)&h[(size_t)s1 * HID + ch];
            const float4 hv2 = *(const float4*)&h[(size_t)s2 * HID + ch];
            const float4 hv3 = *(const float4*)&h[(size_t)s3 * HID + ch];
            a0.x = fmaf(p0, hv0.x, a0.x); a0.y = fmaf(p0, hv0.y, a0.y);
            a0.z = fmaf(p0, hv0.z, a0.z); a0.w = fmaf(p0, hv0.w, a0.w);
            a1.x = fmaf(p1, hv1.x, a1.x); a1.y = fmaf(p1, hv1.y, a1.y);
            a1.z = fmaf(p1, hv1.z, a1.z); a1.w = fmaf(p1, hv1.w, a1.w);
            a2.x = fmaf(p2, hv2.x, a2.x); a2.y = fmaf(p2, hv2.y, a2.y);
            a2.z = fmaf(p2, hv2.z, a2.z); a2.w = fmaf(p2, hv2.w, a2.w);
            a3.x = fmaf(p3, hv3.x, a3.x); a3.y = fmaf(p3, hv3.y, a3.y);
            a3.z = fmaf(p3, hv3.z, a3.z); a3.w = fmaf(p3, hv3.w, a3.w);
        }
        for (; k + 8 <= mainN; k += 8) {
            int   s0 = __shfl(sA, k + q);
            float p0 = __shfl(pA, k + q);
            int   s1 = __shfl(sA, k + 4 + q);
            float p1 = __shfl(pA, k + 4 + q);
            const float4 hv0 = *(const float4*)&h[(size_t)s0 * HID + ch];
            const float4 hv1 = *(const float4*)&h[(size_t)s1 * HID + ch];
            a0.x = fmaf(p0, hv0.x, a0.x); a0.y = fmaf(p0, hv0.y, a0.y);
            a0.z = fmaf(p0, hv0.z, a0.z); a0.w = fmaf(p0, hv0.w, a0.w);
            a1.x = fmaf(p1, hv1.x, a1.x); a1.y = fmaf(p1, hv1.y, a1.y);
            a1.z = fmaf(p1, hv1.z, a1.z); a1.w = fmaf(p1, hv1.w, a1.w);
        }
        for (; k < mainN; k += 4) {
            int   s = __shfl(sA, k + q);
            float p = __shfl(pA, k + q);
            const float4 hv = *(const float4*)&h[(size_t)s * HID + ch];
            a0.x = fmaf(p, hv.x, a0.x); a0.y = fmaf(p, hv.y, a0.y);
            a0.z = fmaf(p, hv.z, a0.z); a0.w = fmaf(p, hv.w, a0.w);
        }
        float4 acc;
        acc.x = (a0.x + a1.x) + (a2.x + a3.x);
        acc.y = (a0.y + a1.y) + (a2.y + a3.y);
        acc.z = (a0.z + a1.z) + (a2.z + a3.z);
        acc.w = (a0.w + a1.w) + (a2.w + a3.w);

        float sumX = 0.f;
        for (int kk0 = k0 + 64; kk0 < k1; kk0 += 4) {
            int kk = kk0 + q;
            bool valid = (kk < k1);
            int s = valid ? sorted_src[kk] : d;
            float e = al_s[s] + ald;
            e = (e > 0.f) ? e : LR_ATT * e;
            float ex = valid ? __expf(e - m) : 0.f;
            const float4 hv = *(const float4*)&h[(size_t)s * HID + ch];
            acc.x = fmaf(ex, hv.x, acc.x);
            acc.y = fmaf(ex, hv.y, acc.y);
            acc.z = fmaf(ex, hv.z, acc.z);
            acc.w = fmaf(ex, hv.w, acc.w);
            sumX += ex;
        }

        #pragma unroll
        for (int off = 16; off <= 32; off <<= 1) {
            acc.x += __shfl_xor(acc.x, off);
            acc.y += __shfl_xor(acc.y, off);
            acc.z += __shfl_xor(acc.z, off);
            acc.w += __shfl_xor(acc.w, off);
            sumX  += __shfl_xor(sumX, off);
        }
        sum += sumX;

        float inv = 1.f / sum;
        float4 v;
        v.x = fmaf(acc.x, inv, bc.x); v.y = fmaf(acc.y, inv, bc.y);
        v.z = fmaf(acc.z, inv, bc.z); v.w = fmaf(acc.w, inv, bc.w);
        v.x = (v.x > 0.f) ? v.x : LR_ACT * v.x;
        v.y = (v.y > 0.f) ? v.y : LR_ACT * v.y;
        v.z = (v.z > 0.f) ? v.z : LR_ACT * v.z;
        v.w = (v.w > 0.f) ? v.w : LR_ACT * v.w;

        if (!FUSE_HEAD) {
            if (lane < 16) *(float4*)&hout[(size_t)d * HID + ch] = v;
        } else {
            float t = v.x * wc.x + v.y * wc.y + v.z * wc.z + v.w * wc.w;
            #pragma unroll
            for (int off = 8; off; off >>= 1) t += __shfl_xor(t, off);
            if (lane == 0) out[d] = t + bout[0];
        }
    }
}

extern "C" void kernel_launch(void* const* d_in, const int* in_sizes, int n_in,
                              void* d_out, int out_size, void* d_ws, size_t ws_size,
                              hipStream_t stream)
{
    const float* x      = (const float*)d_in[0];
    const int*   ei     = (const int*)  d_in[1];
    const float* W1     = (const float*)d_in[2];
    const float* a_src1 = (const float*)d_in[3];
    const float* a_dst1 = (const float*)d_in[4];
    const float* b1     = (const float*)d_in[5];
    const float* W2     = (const float*)d_in[6];
    const float* a_src2 = (const float*)d_in[7];
    const float* a_dst2 = (const float*)d_in[8];
    const float* b2     = (const float*)d_in[9];
    const float* W3     = (const float*)d_in[10];
    const float* a_src3 = (const float*)d_in[11];
    const float* a_dst3 = (const float*)d_in[12];
    const float* b3     = (const float*)d_in[13];
    const float* W_out  = (const float*)d_in[14];
    const float* b_out  = (const float*)d_in[15];
    float* out = (float*)d_out;

    const int n = out_size;           // 50000 nodes
    const int E = in_sizes[1] / 2;    // 1.6M edges
    const int NB = (n + 255) >> BSHIFT;   // 196 buckets (<=256)

    const int* src = ei;
    const int* dst = ei + E;

    // workspace layout; bucketed (E u64) ALIASES hA (consumed before gemm1 writes hA)
    float* ws   = (float*)d_ws;
    size_t reg1 = ((size_t)E * 8 > (size_t)n * HID * 4) ? (size_t)E * 2
                                                        : (size_t)n * HID;  // in floats
    float* hA   = ws;                        // n*64 floats (also bucketed E u64)
    float* hB   = hA + reg1;                 // n*64
    float* al_s = hB + (size_t)n * HID;      // n
    float* al_d = al_s + n;                  // n
    int* bucket_counts = (int*)(al_d + n);   // NB
    int* bucket_off    = bucket_counts + NB; // NB+1
    int* cursor        = bucket_off + NB + 1;// NB
    int* offsets       = cursor + NB;        // n+1
    int* sorted_src    = offsets + (n + 1);  // E
    unsigned long long* bucketed = (unsigned long long*)hA;  // E u64 (256B-aligned ws)

    dim3 blk(256);
    const int node_grid  = (n + 3) / 4;
    const int gemm1_grid = (n + 31) / 32;
    const int gemm2_grid = (n + 63) / 64;
    const int scat_grid  = (E + TILE - 1) / TILE;

    // ---- CSR build via bucket sort (graph is layer-invariant) ----
    (void)hipMemsetAsync(bucket_counts, 0, (size_t)NB * sizeof(int), stream);
    bucket_hist_kernel<<<512, blk, 0, stream>>>(dst, bucket_counts, E, NB);
    bucket_scan_kernel<<<1, blk, 0, stream>>>(bucket_counts, bucket_off, cursor,
        offsets, NB, n, E);
    bucket_scatter_kernel<<<scat_grid, blk, 0, stream>>>(src, dst, cursor,
        bucketed, E, NB);
    bucket_sort_kernel<<<NB, blk, 0, stream>>>(bucketed, bucket_off,
        sorted_src, offsets, n);

    // ---- layer 1 (K = 128) ----
    gemm_tile_kernel<128><<<gemm1_grid, blk, 0, stream>>>(x, W1, a_src1, a_dst1,
        hA, al_s, al_d, n);
    node_agg_kernel<false><<<node_grid, blk, 0, stream>>>(offsets, sorted_src,
        al_s, al_d, hA, b1, hB, nullptr, nullptr, nullptr, n);

    // ---- layer 2 (K = 64) ----
    gemm_tile_kernel<64><<<gemm2_grid, blk, 0, stream>>>(hB, W2, a_src2, a_dst2,
        hA, al_s, al_d, n);
    node_agg_kernel<false><<<node_grid, blk, 0, stream>>>(offsets, sorted_src,
        al_s, al_d, hA, b2, hB, nullptr, nullptr, nullptr, n);

    // ---- layer 3 (K = 64) + fused output head ----
    gemm_tile_kernel<64><<<gemm2_grid, blk, 0, stream>>>(hB, W3, a_src3, a_dst3,
        hA, al_s, al_d, n);
    node_agg_kernel<true><<<node_grid, blk, 0, stream>>>(offsets, sorted_src,
        al_s, al_d, hA, b3, nullptr, W_out, b_out, out, n);
}

// Round 33
// 252.783 us; speedup vs baseline: 1.1531x; 1.1531x over previous
//
#include <hip/hip_runtime.h>
#include <hip/hip_fp16.h>
#include <math.h>

#define HID 64
#define LR_ATT 0.2f
#define LR_ACT 0.01f
#define BSHIFT 8          // bucket = dst >> 8 (256 dsts per bucket)
#define TILE 2048         // edges per bucket_scatter tile

// ---------------- CSR build via 2-level LDS bucket sort (no per-edge global atomics) ----------------

__global__ __launch_bounds__(256) void bucket_hist_kernel(
    const int* __restrict__ dst, int* __restrict__ bucket_counts, int E, int NB)
{
    __shared__ int h[256];
    h[threadIdx.x] = 0;
    __syncthreads();
    int i = blockIdx.x * blockDim.x + threadIdx.x;
    int stride = gridDim.x * blockDim.x;
    for (; i < E; i += stride) atomicAdd(&h[dst[i] >> BSHIFT], 1);
    __syncthreads();
    if (threadIdx.x < NB && h[threadIdx.x])
        atomicAdd(&bucket_counts[threadIdx.x], h[threadIdx.x]);
}

__global__ __launch_bounds__(256) void bucket_scan_kernel(
    const int* __restrict__ bucket_counts, int* __restrict__ bucket_off,
    int* __restrict__ cursor, int* __restrict__ offsets, int NB, int n, int E)
{
    __shared__ int sd[256];
    const int t = threadIdx.x;
    int v = (t < NB) ? bucket_counts[t] : 0;
    sd[t] = v;
    __syncthreads();
    for (int off = 1; off < 256; off <<= 1) {
        int u = (t >= off) ? sd[t - off] : 0;
        __syncthreads();
        sd[t] += u;
        __syncthreads();
    }
    int excl = sd[t] - v;
    if (t < NB) { bucket_off[t] = excl; cursor[t] = excl; }
    if (t == 255) { bucket_off[NB] = sd[255]; offsets[n] = E; }
}

__global__ __launch_bounds__(256) void bucket_scatter_kernel(
    const int* __restrict__ src, const int* __restrict__ dst,
    int* __restrict__ cursor, unsigned long long* __restrict__ bucketed,
    int E, int NB)
{
    constexpr int EPT = TILE / 256;
    __shared__ int cnt[256], lo[256], gb[256];
    __shared__ unsigned long long stg[TILE];

    const int t = threadIdx.x;
    const int base = blockIdx.x * TILE;
    const int tcount = min(TILE, E - base);

    cnt[t] = 0;
    __syncthreads();

    unsigned long long e[EPT];
    int r[EPT], bb[EPT];
    #pragma unroll
    for (int j = 0; j < EPT; ++j) {
        int idx = base + j * 256 + t;
        if (idx < E) {
            int d = dst[idx], s = src[idx];
            e[j]  = ((unsigned long long)(unsigned)d << 32) | (unsigned)s;
            bb[j] = d >> BSHIFT;
            r[j]  = atomicAdd(&cnt[bb[j]], 1);
        } else {
            bb[j] = -1;
        }
    }
    __syncthreads();

    const int v = cnt[t];
    lo[t] = v;
    __syncthreads();
    for (int off = 1; off < 256; off <<= 1) {
        int u = (t >= off) ? lo[t - off] : 0;
        __syncthreads();
        lo[t] += u;
        __syncthreads();
    }
    const int excl = lo[t] - v;
    __syncthreads();
    lo[t] = excl;
    if (t < NB) gb[t] = atomicAdd(&cursor[t], v);
    __syncthreads();

    #pragma unroll
    for (int j = 0; j < EPT; ++j)
        if (bb[j] >= 0) stg[lo[bb[j]] + r[j]] = e[j];
    __syncthreads();

    for (int j = t; j < tcount; j += 256) {
        unsigned long long ev = stg[j];
        int b = (int)(ev >> 32) >> BSHIFT;
        bucketed[gb[b] + (j - lo[b])] = ev;
    }
}

__global__ __launch_bounds__(256) void bucket_sort_kernel(
    const unsigned long long* __restrict__ bucketed,
    const int* __restrict__ bucket_off,
    int* __restrict__ sorted_src, int* __restrict__ offsets, int n)
{
    __shared__ int dcnt[256], loff[256], cur[256];
    const int b = blockIdx.x, t = threadIdx.x;
    const int bo = bucket_off[b], bo1 = bucket_off[b + 1];

    dcnt[t] = 0;
    __syncthreads();
    for (int j = bo + t; j < bo1; j += 256)
        atomicAdd(&dcnt[(int)(bucketed[j] >> 32) & 255], 1);
    __syncthreads();

    const int v = dcnt[t];
    loff[t] = v;
    __syncthreads();
    for (int off = 1; off < 256; off <<= 1) {
        int u = (t >= off) ? loff[t - off] : 0;
        __syncthreads();
        loff[t] += u;
        __syncthreads();
    }
    const int excl = loff[t] - v;
    __syncthreads();
    loff[t] = excl;
    cur[t]  = excl;
    __syncthreads();

    const int d_global = (b << BSHIFT) + t;
    if (d_global < n) offsets[d_global] = bo + excl;

    for (int j = bo + t; j < bo1; j += 256) {
        unsigned long long ev = bucketed[j];
        int d = (int)(ev >> 32);
        int slot = atomicAdd(&cur[d & 255], 1);
        sorted_src[bo + slot] = (int)(ev & 0xffffffffu);
    }
}

// ---------------- per-layer kernels ----------------

// Block-tiled GEMM. Output features written ONLY as fp16 (h16) -- the f32
// features were consumed solely by the PV gather, which now reads fp16
// (halving the dominant gather traffic). al_s/al_d stay f32.
template<int K>
__global__ __launch_bounds__(256) void gemm_tile_kernel(
    const float* __restrict__ hin, const float* __restrict__ W,
    const float* __restrict__ a_src, const float* __restrict__ a_dst,
    __half* __restrict__ h16, float* __restrict__ al_s, float* __restrict__ al_d,
    int n_nodes)
{
    constexpr int TR = (K > 64) ? 32 : 64;
    constexpr int NR = TR / 16;
    constexpr int KP = K + 4;
    constexpr int NK4 = K / 4;

    __shared__ float ws[K * HID];
    __shared__ float xs[TR * KP];

    const int t = threadIdx.x;
    const int base = blockIdx.x * TR;

    for (int i = t; i < K * HID; i += 256) ws[i] = W[i];

    for (int f = t; f < TR * NK4; f += 256) {
        int row = f / NK4, k4 = f % NK4;
        if (base + row < n_nodes)
            *(float4*)&xs[row * KP + k4 * 4] =
                *(const float4*)(hin + (size_t)(base + row) * K + k4 * 4);
    }
    __syncthreads();

    const int ch0 = (t & 15) * 4;
    const int ng  = (t >> 4) * NR;

    float4 acc[NR];
    #pragma unroll
    for (int j = 0; j < NR; ++j) acc[j] = float4{0.f, 0.f, 0.f, 0.f};

    #pragma unroll 4
    for (int k = 0; k < K; ++k) {
        const float4 wv = *(const float4*)&ws[k * HID + ch0];
        #pragma unroll
        for (int j = 0; j < NR; ++j) {
            const float xv = xs[(ng + j) * KP + k];
            acc[j].x = fmaf(xv, wv.x, acc[j].x);
            acc[j].y = fmaf(xv, wv.y, acc[j].y);
            acc[j].z = fmaf(xv, wv.z, acc[j].z);
            acc[j].w = fmaf(xv, wv.w, acc[j].w);
        }
    }

    const float4 as4 = *(const float4*)&a_src[ch0];
    const float4 ad4 = *(const float4*)&a_dst[ch0];

    #pragma unroll
    for (int j = 0; j < NR; ++j) {
        const int row = base + ng + j;
        if (row < n_nodes) {
            __half2* hp = (__half2*)(h16 + (size_t)row * HID + ch0);
            hp[0] = __floats2half2_rn(acc[j].x, acc[j].y);
            hp[1] = __floats2half2_rn(acc[j].z, acc[j].w);
            float ps = acc[j].x * as4.x + acc[j].y * as4.y
                     + acc[j].z * as4.z + acc[j].w * as4.w;
            float pd = acc[j].x * ad4.x + acc[j].y * ad4.y
                     + acc[j].z * ad4.z + acc[j].w * ad4.w;
            #pragma unroll
            for (int off = 8; off; off >>= 1) {
                ps += __shfl_xor(ps, off);
                pd += __shfl_xor(pd, off);
            }
            if ((t & 15) == 0) {
                al_s[row] = ps;
                al_d[row] = pd;
            }
        }
    }
}

__device__ inline float4 load_h16(const __half* __restrict__ h16, size_t idx)
{
    uint2 u = *(const uint2*)(h16 + idx);
    __half2 a = *reinterpret_cast<__half2*>(&u.x);
    __half2 b = *reinterpret_cast<__half2*>(&u.y);
    float2 fa = __half22float2(a);
    float2 fb = __half22float2(b);
    return float4{fa.x, fa.y, fb.x, fb.y};
}

// One wave per dst node; precomputed softmax, 2-stream fp16 gathers
// (8B/lane/edge -> 128B/wave/edge, half the f32 traffic).
template<bool FUSE_HEAD>
__global__ __launch_bounds__(256) void node_agg_kernel(
    const int* __restrict__ offsets, const int* __restrict__ sorted_src,
    const float* __restrict__ al_s, const float* __restrict__ al_d,
    const __half* __restrict__ h16, const float* __restrict__ b,
    float* __restrict__ hout,
    const float* __restrict__ Wout, const float* __restrict__ bout,
    float* __restrict__ out, int n_nodes)
{
    const int lane = threadIdx.x & 63;
    const int q    = lane >> 4;
    const int ch   = (lane & 15) * 4;
    const int wib  = threadIdx.x >> 6;
    const int wpb  = blockDim.x >> 6;
    int wid = blockIdx.x * wpb + wib;
    int nw  = gridDim.x * wpb;

    const float4 bc = *(const float4*)&b[ch];
    const float4 wc = FUSE_HEAD ? *(const float4*)&Wout[ch] : float4{0.f,0.f,0.f,0.f};

    for (int d = wid; d < n_nodes; d += nw) {
        const float ald = al_d[d];
        float e0 = al_s[d] + ald;
        e0 = (e0 > 0.f) ? e0 : LR_ATT * e0;

        const int k0  = offsets[d];
        const int k1  = offsets[d + 1];
        const int deg = k1 - k0;

        int   sA = d;
        float eA = __int_as_float(0xff800000);
        if (lane < deg) {
            sA = sorted_src[k0 + lane];
            float e = al_s[sA] + ald;
            eA = (e > 0.f) ? e : LR_ATT * e;
        }
        float lm = fmaxf(e0, eA);
        for (int k = k0 + 64 + lane; k < k1; k += 64) {
            int s = sorted_src[k];
            float e = al_s[s] + ald;
            e = (e > 0.f) ? e : LR_ATT * e;
            lm = fmaxf(lm, e);
        }
        #pragma unroll
        for (int off = 32; off; off >>= 1)
            lm = fmaxf(lm, __shfl_xor(lm, off));
        const float m = lm;

        const float ex0 = __expf(e0 - m);
        float pA = (lane < deg) ? __expf(eA - m) : 0.f;
        float ssum = pA;
        #pragma unroll
        for (int off = 32; off; off >>= 1) ssum += __shfl_xor(ssum, off);
        float sum = ssum + ex0;

        const float4 hd = load_h16(h16, (size_t)d * HID + ch);
        float exq = (q == 0) ? ex0 : 0.f;
        float4 acc, acc2;
        acc.x  = exq * hd.x; acc.y  = exq * hd.y;
        acc.z  = exq * hd.z; acc.w  = exq * hd.w;
        acc2.x = 0.f; acc2.y = 0.f; acc2.z = 0.f; acc2.w = 0.f;

        const int mainN = min(deg, 64);
        int k = 0;
        for (; k + 8 <= mainN; k += 8) {
            int   s0 = __shfl(sA, k + q);
            float p0 = __shfl(pA, k + q);
            int   s1 = __shfl(sA, k + 4 + q);
            float p1 = __shfl(pA, k + 4 + q);
            const float4 hv0 = load_h16(h16, (size_t)s0 * HID + ch);
            const float4 hv1 = load_h16(h16, (size_t)s1 * HID + ch);
            acc.x  = fmaf(p0, hv0.x, acc.x);
            acc.y  = fmaf(p0, hv0.y, acc.y);
            acc.z  = fmaf(p0, hv0.z, acc.z);
            acc.w  = fmaf(p0, hv0.w, acc.w);
            acc2.x = fmaf(p1, hv1.x, acc2.x);
            acc2.y = fmaf(p1, hv1.y, acc2.y);
            acc2.z = fmaf(p1, hv1.z, acc2.z);
            acc2.w = fmaf(p1, hv1.w, acc2.w);
        }
        for (; k < mainN; k += 4) {
            int   s = __shfl(sA, k + q);
            float p = __shfl(pA, k + q);
            const float4 hv = load_h16(h16, (size_t)s * HID + ch);
            acc.x = fmaf(p, hv.x, acc.x);
            acc.y = fmaf(p, hv.y, acc.y);
            acc.z = fmaf(p, hv.z, acc.z);
            acc.w = fmaf(p, hv.w, acc.w);
        }
        acc.x += acc2.x; acc.y += acc2.y; acc.z += acc2.z; acc.w += acc2.w;

        float sumX = 0.f;
        for (int kk0 = k0 + 64; kk0 < k1; kk0 += 4) {
            int kk = kk0 + q;
            bool valid = (kk < k1);
            int s = valid ? sorted_src[kk] : d;
            float e = al_s[s] + ald;
            e = (e > 0.f) ? e : LR_ATT * e;
            float ex = valid ? __expf(e - m) : 0.f;
            const float4 hv = load_h16(h16, (size_t)s * HID + ch);
            acc.x = fmaf(ex, hv.x, acc.x);
            acc.y = fmaf(ex, hv.y, acc.y);
            acc.z = fmaf(ex, hv.z, acc.z);
            acc.w = fmaf(ex, hv.w, acc.w);
            sumX += ex;
        }

        #pragma unroll
        for (int off = 16; off <= 32; off <<= 1) {
            acc.x += __shfl_xor(acc.x, off);
            acc.y += __shfl_xor(acc.y, off);
            acc.z += __shfl_xor(acc.z, off);
            acc.w += __shfl_xor(acc.w, off);
            sumX  += __shfl_xor(sumX, off);
        }
        sum += sumX;

        float inv = 1.f / sum;
        float4 v;
        v.x = fmaf(acc.x, inv, bc.x); v.y = fmaf(acc.y, inv, bc.y);
        v.z = fmaf(acc.z, inv, bc.z); v.w = fmaf(acc.w, inv, bc.w);
        v.x = (v.x > 0.f) ? v.x : LR_ACT * v.x;
        v.y = (v.y > 0.f) ? v.y : LR_ACT * v.y;
        v.z = (v.z > 0.f) ? v.z : LR_ACT * v.z;
        v.w = (v.w > 0.f) ? v.w : LR_ACT * v.w;

        if (!FUSE_HEAD) {
            if (lane < 16) *(float4*)&hout[(size_t)d * HID + ch] = v;
        } else {
            float t = v.x * wc.x + v.y * wc.y + v.z * wc.z + v.w * wc.w;
            #pragma unroll
            for (int off = 8; off; off >>= 1) t += __shfl_xor(t, off);
            if (lane == 0) out[d] = t + bout[0];
        }
    }
}

extern "C" void kernel_launch(void* const* d_in, const int* in_sizes, int n_in,
                              void* d_out, int out_size, void* d_ws, size_t ws_size,
                              hipStream_t stream)
{
    const float* x      = (const float*)d_in[0];
    const int*   ei     = (const int*)  d_in[1];
    const float* W1     = (const float*)d_in[2];
    const float* a_src1 = (const float*)d_in[3];
    const float* a_dst1 = (const float*)d_in[4];
    const float* b1     = (const float*)d_in[5];
    const float* W2     = (const float*)d_in[6];
    const float* a_src2 = (const float*)d_in[7];
    const float* a_dst2 = (const float*)d_in[8];
    const float* b2     = (const float*)d_in[9];
    const float* W3     = (const float*)d_in[10];
    const float* a_src3 = (const float*)d_in[11];
    const float* a_dst3 = (const float*)d_in[12];
    const float* b3     = (const float*)d_in[13];
    const float* W_out  = (const float*)d_in[14];
    const float* b_out  = (const float*)d_in[15];
    float* out = (float*)d_out;

    const int n = out_size;           // 50000 nodes
    const int E = in_sizes[1] / 2;    // 1.6M edges
    const int NB = (n + 255) >> BSHIFT;   // 196 buckets (<=256)

    const int* src = ei;
    const int* dst = ei + E;

    // workspace layout; bucketed (E u64) ALIASES hA (consumed before layer 2 writes hA)
    float* ws   = (float*)d_ws;
    size_t reg1 = ((size_t)E * 8 > (size_t)n * HID * 4) ? (size_t)E * 2
                                                        : (size_t)n * HID;  // in floats
    float* hA   = ws;                        // n*64 floats (also bucketed E u64)
    float* hB   = hA + reg1;                 // n*64
    float* al_s = hB + (size_t)n * HID;      // n
    float* al_d = al_s + n;                  // n
    int* bucket_counts = (int*)(al_d + n);   // NB
    int* bucket_off    = bucket_counts + NB; // NB+1
    int* cursor        = bucket_off + NB + 1;// NB
    int* offsets       = cursor + NB;        // n+1
    int* sorted_src    = offsets + (n + 1);  // E
    __half* h16        = (__half*)(sorted_src + E);          // n*64 halves
    unsigned long long* bucketed = (unsigned long long*)hA;  // E u64

    dim3 blk(256);
    const int node_grid  = (n + 3) / 4;
    const int gemm1_grid = (n + 31) / 32;
    const int gemm2_grid = (n + 63) / 64;
    const int scat_grid  = (E + TILE - 1) / TILE;

    // ---- CSR build via bucket sort (graph is layer-invariant) ----
    (void)hipMemsetAsync(bucket_counts, 0, (size_t)NB * sizeof(int), stream);
    bucket_hist_kernel<<<512, blk, 0, stream>>>(dst, bucket_counts, E, NB);
    bucket_scan_kernel<<<1, blk, 0, stream>>>(bucket_counts, bucket_off, cursor,
        offsets, NB, n, E);
    bucket_scatter_kernel<<<scat_grid, blk, 0, stream>>>(src, dst, cursor,
        bucketed, E, NB);
    bucket_sort_kernel<<<NB, blk, 0, stream>>>(bucketed, bucket_off,
        sorted_src, offsets, n);

    // ---- layer 1 (K = 128) ----
    gemm_tile_kernel<128><<<gemm1_grid, blk, 0, stream>>>(x, W1, a_src1, a_dst1,
        h16, al_s, al_d, n);
    node_agg_kernel<false><<<node_grid, blk, 0, stream>>>(offsets, sorted_src,
        al_s, al_d, h16, b1, hB, nullptr, nullptr, nullptr, n);

    // ---- layer 2 (K = 64) ----
    gemm_tile_kernel<64><<<gemm2_grid, blk, 0, stream>>>(hB, W2, a_src2, a_dst2,
        h16, al_s, al_d, n);
    node_agg_kernel<false><<<node_grid, blk, 0, stream>>>(offsets, sorted_src,
        al_s, al_d, h16, b2, hA, nullptr, nullptr, nullptr, n);

    // ---- layer 3 (K = 64) + fused output head ----
    gemm_tile_kernel<64><<<gemm2_grid, blk, 0, stream>>>(hA, W3, a_src3, a_dst3,
        h16, al_s, al_d, n);
    node_agg_kernel<true><<<node_grid, blk, 0, stream>>>(offsets, sorted_src,
        al_s, al_d, h16, b3, nullptr, W_out, b_out, out, n);
}